// Round 6
// baseline (146.778 us; speedup 1.0000x reference)
//
#include <hip/hip_runtime.h>
#include <math.h>

#define B_TOT 8192
#define D_ 64
#define W_ 128
#define H_ 128
#define NCOL 256

typedef float f32x4 __attribute__((ext_vector_type(4)));

// ws float offsets
#define WS_FWM     0        // 384*256 folded main weights (k-major)
#define WS_FWMEM   98304    // 384*3 folded mem-head weights
#define WS_BIASM   99456    // 256 folded main bias
#define WS_BIASMEM 99712    // 3 folded mem bias

// out float offsets (return order: stack_new, next_state, logits_buf, action_probs)
#define OUT_STACK 0
#define OUT_STATE 67108864UL
#define OUT_BUF   68157440UL
#define OUT_PROBS 69206016UL

#define NB_GEMM 1024   // 8 batch rows per GEMM block
#define NB_STEN 4096   // 2 batch rows per stencil block
#define BROWS 8
#define ACT_PAD 388    // 384 + 4 pad

__global__ __launch_bounds__(256) void fold_kernel(
    const float* __restrict__ W_state, const float* __restrict__ b_state,
    const float* __restrict__ W_top,   const float* __restrict__ b_top,
    const float* __restrict__ W_mem,   const float* __restrict__ b_mem,
    const float* __restrict__ W_buf,   const float* __restrict__ b_buf,
    const float* __restrict__ W_stateout, const float* __restrict__ b_stateout,
    float* __restrict__ ws)
{
    int k = blockIdx.x;   // 0..383
    int j = threadIdx.x;  // 0..255
    int col = j & 127;
    const float* Whead = (j < 128) ? W_buf : W_stateout;
    const float* bhead = (j < 128) ? b_buf : b_stateout;
    float v;
    if (k < 128) {
        v = Whead[k*H_ + col];
    } else if (k < 256) {
        const float* a = W_state + (size_t)(k-128)*H_;
        float s = 0.f;
        for (int t = 0; t < 128; ++t) s += a[t] * Whead[(128+t)*H_ + col];
        v = s;
    } else {
        const float* a = W_top + (size_t)(k-256)*H_;
        float s = 0.f;
        for (int t = 0; t < 128; ++t) s += a[t] * Whead[(256+t)*H_ + col];
        v = s;
    }
    ws[WS_FWM + k*NCOL + j] = v;

    if (j < 3) {
        float v2;
        if (k < 128) v2 = W_mem[k*3 + j];
        else if (k < 256) {
            const float* a = W_state + (size_t)(k-128)*H_;
            float s = 0.f;
            for (int t = 0; t < 128; ++t) s += a[t] * W_mem[(128+t)*3 + j];
            v2 = s;
        } else {
            const float* a = W_top + (size_t)(k-256)*H_;
            float s = 0.f;
            for (int t = 0; t < 128; ++t) s += a[t] * W_mem[(256+t)*3 + j];
            v2 = s;
        }
        ws[WS_FWMEM + k*3 + j] = v2;
    }
    if (k == 0) {
        float s = bhead[col];
        for (int t = 0; t < 128; ++t)
            s += b_state[t]*Whead[(128+t)*H_ + col] + b_top[t]*Whead[(256+t)*H_ + col];
        ws[WS_BIASM + j] = s;
        if (j < 3) {
            float s2 = b_mem[j];
            for (int t = 0; t < 128; ++t)
                s2 += b_state[t]*W_mem[(128+t)*3 + j] + b_top[t]*W_mem[(256+t)*3 + j];
            ws[WS_BIASMEM + j] = s2;
        }
    }
}

__global__ __launch_bounds__(256) void main_kernel(
    const float* __restrict__ stack, const float* __restrict__ state_prev,
    const float* __restrict__ x_emb, const float* __restrict__ ws,
    float* __restrict__ out)
{
    int tid = threadIdx.x;
    __shared__ float act[BROWS * ACT_PAD];   // 12.4 KB -> 8 blocks/CU (wave-capped)
    __shared__ float psh[2][3];

    if (blockIdx.x < NB_GEMM) {
        // ---- GEMM role: 8 rows x 256 cols, LDS-staged acts + 2x4 register tile
        int b0 = blockIdx.x * BROWS;

        // stage [8][384]: each segment (128 floats x 8 rows) = 256 float4 = 1/thread
        #pragma unroll
        for (int s = 0; s < 3; ++s) {
            int r  = tid >> 5;             // 0..7
            int kk = (tid & 31) << 2;      // 0..124
            const float* src;
            if (s == 0)      src = x_emb      + (size_t)(b0+r)*H_;
            else if (s == 1) src = state_prev + (size_t)(b0+r)*H_;
            else             src = stack      + (size_t)(b0+r)*(D_*W_);
            f32x4 v = *(const f32x4*)(src + kk);
            *(f32x4*)(act + r*ACT_PAD + s*128 + kk) = v;
        }
        __syncthreads();

        int rg = tid >> 6;         // 0..3 -> rows 2*rg, 2*rg+1 (wave-uniform)
        int cg = tid & 63;         // 0..63 -> cols 4*cg
        const float* __restrict__ FW = ws + WS_FWM;
        f32x4 bj = *(const f32x4*)(ws + WS_BIASM + 4*cg);
        float acc[2][4];
        #pragma unroll
        for (int r = 0; r < 2; ++r) {
            acc[r][0] = bj.x; acc[r][1] = bj.y; acc[r][2] = bj.z; acc[r][3] = bj.w;
        }
        const float* a0p = act + (2*rg+0)*ACT_PAD;
        const float* a1p = act + (2*rg+1)*ACT_PAD;

        #pragma unroll 8
        for (int k = 0; k < 384; ++k) {
            f32x4 w = *(const f32x4*)(FW + (size_t)k*NCOL + 4*cg);
            float a0 = a0p[k], a1 = a1p[k];
            acc[0][0] += a0*w.x; acc[0][1] += a0*w.y; acc[0][2] += a0*w.z; acc[0][3] += a0*w.w;
            acc[1][0] += a1*w.x; acc[1][1] += a1*w.y; acc[1][2] += a1*w.z; acc[1][3] += a1*w.w;
        }

        #pragma unroll
        for (int r = 0; r < 2; ++r) {
            size_t row = (size_t)(b0 + 2*rg + r);
            if (cg < 32) {
                f32x4 o = {acc[r][0], acc[r][1], acc[r][2], acc[r][3]};
                __builtin_nontemporal_store(o, (f32x4*)(out + OUT_BUF + row*H_ + 4*cg));
            } else {
                f32x4 o = {tanhf(acc[r][0]), tanhf(acc[r][1]),
                           tanhf(acc[r][2]), tanhf(acc[r][3])};
                __builtin_nontemporal_store(o, (f32x4*)(out + OUT_STATE + row*H_ + (4*cg - 128)));
            }
        }
    } else {
        // ---- Stencil role: wave-reduce probs head + barrier-free stream ----
        int blk  = blockIdx.x - NB_GEMM;     // 0..4095
        int wv   = tid >> 6;
        int lane = tid & 63;

        if ((wv & 1) == 0) {                 // waves 0,2 compute probs for rows 0,1
            int bb = blk*2 + (wv >> 1);
            const float* __restrict__ FM = ws + WS_FWMEM;
            float a0 = 0.f, a1 = 0.f, a2 = 0.f;
            int kbase = lane * 6;
            #pragma unroll
            for (int jj = 0; jj < 6; ++jj) {
                int k = kbase + jj;
                float x;
                if (k < 128)      x = x_emb[(size_t)bb*H_ + k];
                else if (k < 256) x = state_prev[(size_t)bb*H_ + (k-128)];
                else              x = stack[(size_t)bb*(D_*W_) + (k-256)];
                a0 += x * FM[k*3+0];
                a1 += x * FM[k*3+1];
                a2 += x * FM[k*3+2];
            }
            #pragma unroll
            for (int m = 1; m < 64; m <<= 1) {
                a0 += __shfl_xor(a0, m);
                a1 += __shfl_xor(a1, m);
                a2 += __shfl_xor(a2, m);
            }
            if (lane == 0) {
                float l0 = a0 + ws[WS_BIASMEM+0];
                float l1 = a1 + ws[WS_BIASMEM+1];
                float l2 = a2 + ws[WS_BIASMEM+2];
                float mm = fmaxf(l0, fmaxf(l1, l2));
                float e0 = __expf(l0-mm), e1 = __expf(l1-mm), e2 = __expf(l2-mm);
                float inv = 1.f / (e0+e1+e2);
                int ro = wv >> 1;
                psh[ro][0] = e0*inv; psh[ro][1] = e1*inv; psh[ro][2] = e2*inv;
                __builtin_nontemporal_store(e0*inv, out + OUT_PROBS + (size_t)bb*3 + 0);
                __builtin_nontemporal_store(e1*inv, out + OUT_PROBS + (size_t)bb*3 + 1);
                __builtin_nontemporal_store(e2*inv, out + OUT_PROBS + (size_t)bb*3 + 2);
            }
        }
        __syncthreads();

        int w4  = tid & 31;                  // float4 index within width-128 row
        int seg = (tid >> 5) & 3;            // depth segment of 16
        int bo  = tid >> 7;                  // 0..1
        size_t b = (size_t)blk * 2 + bo;
        float p0 = psh[bo][0], p1 = psh[bo][1], p2 = psh[bo][2];

        const f32x4* sp = (const f32x4*)(stack + b*(D_*W_)) + w4;
        f32x4*       op = (f32x4*)(out + OUT_STACK + b*(D_*W_)) + w4;

        int d0 = seg * 16;
        f32x4 cur  = sp[(size_t)d0*32];
        f32x4 prev = (d0 == 0) ? cur : sp[(size_t)(d0-1)*32];
        #pragma unroll
        for (int h = 0; h < 2; ++h) {
            int base = d0 + h*8;
            f32x4 nx[8];
            #pragma unroll
            for (int i = 0; i < 8; ++i) {
                int d = base + i + 1;
                if (d < 64) nx[i] = sp[(size_t)d*32];
                else        nx[i] = (f32x4){0.f, 0.f, 0.f, 0.f};
            }
            #pragma unroll
            for (int i = 0; i < 8; ++i) {
                int d = base + i;
                f32x4 o = p0*prev + p1*nx[i] + p2*cur;
                __builtin_nontemporal_store(o, op + (size_t)d*32);
                prev = cur; cur = nx[i];
            }
        }
    }
}

extern "C" void kernel_launch(void* const* d_in, const int* in_sizes, int n_in,
                              void* d_out, int out_size, void* d_ws, size_t ws_size,
                              hipStream_t stream) {
    const float* stack      = (const float*)d_in[0];
    const float* state_prev = (const float*)d_in[1];
    const float* x_emb      = (const float*)d_in[2];
    const float* W_state    = (const float*)d_in[3];
    const float* b_state    = (const float*)d_in[4];
    const float* W_top      = (const float*)d_in[5];
    const float* b_top      = (const float*)d_in[6];
    const float* W_mem      = (const float*)d_in[7];
    const float* b_mem      = (const float*)d_in[8];
    const float* W_buf      = (const float*)d_in[9];
    const float* b_buf      = (const float*)d_in[10];
    const float* W_stateout = (const float*)d_in[11];
    const float* b_stateout = (const float*)d_in[12];
    float* out = (float*)d_out;
    float* ws  = (float*)d_ws;

    hipLaunchKernelGGL(fold_kernel, dim3(384), dim3(256), 0, stream,
        W_state, b_state, W_top, b_top, W_mem, b_mem,
        W_buf, b_buf, W_stateout, b_stateout, ws);
    hipLaunchKernelGGL(main_kernel, dim3(NB_GEMM + NB_STEN), dim3(256), 0, stream,
        stack, state_prev, x_emb, ws, out);
}

// Round 7
// 141.710 us; speedup vs baseline: 1.0358x; 1.0358x over previous
//
#include <hip/hip_runtime.h>
#include <math.h>

#define B_TOT 8192
#define D_ 64
#define W_ 128
#define H_ 128
#define NCOL 256

typedef float f32x4 __attribute__((ext_vector_type(4)));

// ws float offsets
#define WS_FWM     0        // 384*256 folded main weights (k-major)
#define WS_FWMEM   98304    // 384*3 folded mem-head weights
#define WS_BIASM   99456    // 256 folded main bias
#define WS_BIASMEM 99712    // 3 folded mem bias

// out float offsets (return order: stack_new, next_state, logits_buf, action_probs)
#define OUT_STACK 0
#define OUT_STATE 67108864UL
#define OUT_BUF   68157440UL
#define OUT_PROBS 69206016UL

#define NB_GEMM 512
#define NB_STEN 4096   // 2 batch rows per block
#define BROWS 16
#define ACT_PAD 388    // 384 + 4 pad

__global__ __launch_bounds__(256) void fold_kernel(
    const float* __restrict__ W_state, const float* __restrict__ b_state,
    const float* __restrict__ W_top,   const float* __restrict__ b_top,
    const float* __restrict__ W_mem,   const float* __restrict__ b_mem,
    const float* __restrict__ W_buf,   const float* __restrict__ b_buf,
    const float* __restrict__ W_stateout, const float* __restrict__ b_stateout,
    float* __restrict__ ws)
{
    int k = blockIdx.x;   // 0..383
    int j = threadIdx.x;  // 0..255
    int col = j & 127;
    const float* Whead = (j < 128) ? W_buf : W_stateout;
    const float* bhead = (j < 128) ? b_buf : b_stateout;
    float v;
    if (k < 128) {
        v = Whead[k*H_ + col];
    } else if (k < 256) {
        const float* a = W_state + (size_t)(k-128)*H_;
        float s = 0.f;
        for (int t = 0; t < 128; ++t) s += a[t] * Whead[(128+t)*H_ + col];
        v = s;
    } else {
        const float* a = W_top + (size_t)(k-256)*H_;
        float s = 0.f;
        for (int t = 0; t < 128; ++t) s += a[t] * Whead[(256+t)*H_ + col];
        v = s;
    }
    ws[WS_FWM + k*NCOL + j] = v;

    if (j < 3) {
        float v2;
        if (k < 128) v2 = W_mem[k*3 + j];
        else if (k < 256) {
            const float* a = W_state + (size_t)(k-128)*H_;
            float s = 0.f;
            for (int t = 0; t < 128; ++t) s += a[t] * W_mem[(128+t)*3 + j];
            v2 = s;
        } else {
            const float* a = W_top + (size_t)(k-256)*H_;
            float s = 0.f;
            for (int t = 0; t < 128; ++t) s += a[t] * W_mem[(256+t)*3 + j];
            v2 = s;
        }
        ws[WS_FWMEM + k*3 + j] = v2;
    }
    if (k == 0) {
        float s = bhead[col];
        for (int t = 0; t < 128; ++t)
            s += b_state[t]*Whead[(128+t)*H_ + col] + b_top[t]*Whead[(256+t)*H_ + col];
        ws[WS_BIASM + j] = s;
        if (j < 3) {
            float s2 = b_mem[j];
            for (int t = 0; t < 128; ++t)
                s2 += b_state[t]*W_mem[(128+t)*3 + j] + b_top[t]*W_mem[(256+t)*3 + j];
            ws[WS_BIASMEM + j] = s2;
        }
    }
}

// Kernel A: GEMM (16 rows x 256 cols) + mem-head softmax from the same LDS acts.
__global__ __launch_bounds__(256) void gemm_kernel(
    const float* __restrict__ stack, const float* __restrict__ state_prev,
    const float* __restrict__ x_emb, const float* __restrict__ ws,
    float* __restrict__ out)
{
    int tid = threadIdx.x;
    __shared__ float act[BROWS * ACT_PAD];   // 24.8 KB
    int b0 = blockIdx.x * BROWS;

    #pragma unroll
    for (int s = 0; s < 3; ++s) {
        #pragma unroll
        for (int it = 0; it < 2; ++it) {
            int idx = it*256 + tid;        // 0..511
            int r   = idx >> 5;            // 0..15
            int kk  = (idx & 31) << 2;     // 0..124
            const float* src;
            if (s == 0)      src = x_emb      + (size_t)(b0+r)*H_;
            else if (s == 1) src = state_prev + (size_t)(b0+r)*H_;
            else             src = stack      + (size_t)(b0+r)*(D_*W_);
            f32x4 v = *(const f32x4*)(src + kk);
            *(f32x4*)(act + r*ACT_PAD + s*128 + kk) = v;
        }
    }
    __syncthreads();

    int rg = tid & 3;          // row group
    int cg = tid >> 2;         // col group
    const float* __restrict__ FW = ws + WS_FWM;
    f32x4 bj = *(const f32x4*)(ws + WS_BIASM + 4*cg);
    float acc[4][4];
    #pragma unroll
    for (int r = 0; r < 4; ++r) {
        acc[r][0] = bj.x; acc[r][1] = bj.y; acc[r][2] = bj.z; acc[r][3] = bj.w;
    }
    const float* a0p = act + (4*rg+0)*ACT_PAD;
    const float* a1p = act + (4*rg+1)*ACT_PAD;
    const float* a2p = act + (4*rg+2)*ACT_PAD;
    const float* a3p = act + (4*rg+3)*ACT_PAD;

    #pragma unroll 4
    for (int k = 0; k < 384; ++k) {
        f32x4 w = *(const f32x4*)(FW + (size_t)k*NCOL + 4*cg);
        float a0 = a0p[k], a1 = a1p[k], a2 = a2p[k], a3 = a3p[k];
        acc[0][0] += a0*w.x; acc[0][1] += a0*w.y; acc[0][2] += a0*w.z; acc[0][3] += a0*w.w;
        acc[1][0] += a1*w.x; acc[1][1] += a1*w.y; acc[1][2] += a1*w.z; acc[1][3] += a1*w.w;
        acc[2][0] += a2*w.x; acc[2][1] += a2*w.y; acc[2][2] += a2*w.z; acc[2][3] += a2*w.w;
        acc[3][0] += a3*w.x; acc[3][1] += a3*w.y; acc[3][2] += a3*w.z; acc[3][3] += a3*w.w;
    }

    #pragma unroll
    for (int r = 0; r < 4; ++r) {
        size_t row = (size_t)(b0 + 4*rg + r);
        if (cg < 32) {
            f32x4 o = {acc[r][0], acc[r][1], acc[r][2], acc[r][3]};
            __builtin_nontemporal_store(o, (f32x4*)(out + OUT_BUF + row*H_ + 4*cg));
        } else {
            f32x4 o = {tanhf(acc[r][0]), tanhf(acc[r][1]),
                       tanhf(acc[r][2]), tanhf(acc[r][3])};
            __builtin_nontemporal_store(o, (f32x4*)(out + OUT_STATE + row*H_ + (4*cg - 128)));
        }
    }

    // ---- mem-head + softmax for the 16 rows, from LDS acts (still valid).
    int wv = tid >> 6, lane = tid & 63;
    const float* __restrict__ FM = ws + WS_FWMEM;
    float fm[6][3];
    #pragma unroll
    for (int jj = 0; jj < 6; ++jj) {
        int k = lane*6 + jj;
        fm[jj][0] = FM[k*3+0]; fm[jj][1] = FM[k*3+1]; fm[jj][2] = FM[k*3+2];
    }
    for (int r = wv; r < BROWS; r += 4) {
        const float* ap = act + r*ACT_PAD + lane*6;
        float a0 = 0.f, a1 = 0.f, a2 = 0.f;
        #pragma unroll
        for (int jj = 0; jj < 6; ++jj) {
            float x = ap[jj];
            a0 += x * fm[jj][0];
            a1 += x * fm[jj][1];
            a2 += x * fm[jj][2];
        }
        #pragma unroll
        for (int m = 1; m < 64; m <<= 1) {
            a0 += __shfl_xor(a0, m);
            a1 += __shfl_xor(a1, m);
            a2 += __shfl_xor(a2, m);
        }
        if (lane == 0) {
            float l0 = a0 + ws[WS_BIASMEM+0];
            float l1 = a1 + ws[WS_BIASMEM+1];
            float l2 = a2 + ws[WS_BIASMEM+2];
            float mm = fmaxf(l0, fmaxf(l1, l2));
            float e0 = __expf(l0-mm), e1 = __expf(l1-mm), e2 = __expf(l2-mm);
            float inv = 1.f / (e0+e1+e2);
            size_t bb = (size_t)(b0 + r);
            out[OUT_PROBS + bb*3 + 0] = e0*inv;   // temporal: re-read by stencil kernel
            out[OUT_PROBS + bb*3 + 1] = e1*inv;
            out[OUT_PROBS + bb*3 + 2] = e2*inv;
        }
    }
}

// Kernel B: pure stencil stream. No LDS, no barriers. 2 rows per block.
__global__ __launch_bounds__(256) void stencil_kernel(
    const float* __restrict__ stack, float* __restrict__ out)
{
    int tid = threadIdx.x;
    int w4  = tid & 31;                  // float4 index within width-128 row
    int seg = (tid >> 5) & 3;            // depth segment of 16
    int bo  = tid >> 7;                  // 0..1
    size_t b = (size_t)blockIdx.x * 2 + bo;

    float p0 = out[OUT_PROBS + b*3 + 0];
    float p1 = out[OUT_PROBS + b*3 + 1];
    float p2 = out[OUT_PROBS + b*3 + 2];

    const f32x4* sp = (const f32x4*)(stack + b*(D_*W_)) + w4;
    f32x4*       op = (f32x4*)(out + OUT_STACK + b*(D_*W_)) + w4;

    int d0 = seg * 16;
    f32x4 cur  = sp[(size_t)d0*32];
    f32x4 prev = (d0 == 0) ? cur : sp[(size_t)(d0-1)*32];
    #pragma unroll
    for (int h = 0; h < 2; ++h) {
        int base = d0 + h*8;
        f32x4 nx[8];
        #pragma unroll
        for (int i = 0; i < 8; ++i) {
            int d = base + i + 1;
            if (d < 64) nx[i] = sp[(size_t)d*32];
            else        nx[i] = (f32x4){0.f, 0.f, 0.f, 0.f};
        }
        #pragma unroll
        for (int i = 0; i < 8; ++i) {
            int d = base + i;
            f32x4 o = p0*prev + p1*nx[i] + p2*cur;
            __builtin_nontemporal_store(o, op + (size_t)d*32);
            prev = cur; cur = nx[i];
        }
    }
}

extern "C" void kernel_launch(void* const* d_in, const int* in_sizes, int n_in,
                              void* d_out, int out_size, void* d_ws, size_t ws_size,
                              hipStream_t stream) {
    const float* stack      = (const float*)d_in[0];
    const float* state_prev = (const float*)d_in[1];
    const float* x_emb      = (const float*)d_in[2];
    const float* W_state    = (const float*)d_in[3];
    const float* b_state    = (const float*)d_in[4];
    const float* W_top      = (const float*)d_in[5];
    const float* b_top      = (const float*)d_in[6];
    const float* W_mem      = (const float*)d_in[7];
    const float* b_mem      = (const float*)d_in[8];
    const float* W_buf      = (const float*)d_in[9];
    const float* b_buf      = (const float*)d_in[10];
    const float* W_stateout = (const float*)d_in[11];
    const float* b_stateout = (const float*)d_in[12];
    float* out = (float*)d_out;
    float* ws  = (float*)d_ws;

    hipLaunchKernelGGL(fold_kernel, dim3(384), dim3(256), 0, stream,
        W_state, b_state, W_top, b_top, W_mem, b_mem,
        W_buf, b_buf, W_stateout, b_stateout, ws);
    hipLaunchKernelGGL(gemm_kernel, dim3(NB_GEMM), dim3(256), 0, stream,
        stack, state_prev, x_emb, ws, out);
    hipLaunchKernelGGL(stencil_kernel, dim3(NB_STEN), dim3(256), 0, stream,
        stack, out);
}

// Round 8
// 112.714 us; speedup vs baseline: 1.3022x; 1.2573x over previous
//
#include <hip/hip_runtime.h>
#include <math.h>

#define B_TOT 8192
#define D_ 64
#define W_ 128
#define H_ 128
#define NCOL 256

typedef float f32x4 __attribute__((ext_vector_type(4)));

// ws float offsets
#define WS_FWM     0        // 384*256 folded main weights (k-major)
#define WS_FWMEM   98304    // 384*3 folded mem-head weights
#define WS_BIASM   99456    // 256 folded main bias
#define WS_BIASMEM 99712    // 3 folded mem bias

// out float offsets (return order: stack_new, next_state, logits_buf, action_probs)
#define OUT_STACK 0
#define OUT_STATE 67108864UL
#define OUT_BUF   68157440UL
#define OUT_PROBS 69206016UL

#define NB_GEMM 512
#define NB_STEN 4096   // 2 batch rows per block
#define BROWS 16
#define ACT_PAD 388    // 384 + 4 pad
#define B_CACHED 5632  // rows < this: normal (L3-resident) loads; >=: nontemporal stream

__global__ __launch_bounds__(256) void fold_kernel(
    const float* __restrict__ W_state, const float* __restrict__ b_state,
    const float* __restrict__ W_top,   const float* __restrict__ b_top,
    const float* __restrict__ W_mem,   const float* __restrict__ b_mem,
    const float* __restrict__ W_buf,   const float* __restrict__ b_buf,
    const float* __restrict__ W_stateout, const float* __restrict__ b_stateout,
    float* __restrict__ ws)
{
    int k = blockIdx.x;   // 0..383
    int j = threadIdx.x;  // 0..255
    int col = j & 127;
    const float* Whead = (j < 128) ? W_buf : W_stateout;
    const float* bhead = (j < 128) ? b_buf : b_stateout;
    float v;
    if (k < 128) {
        v = Whead[k*H_ + col];
    } else if (k < 256) {
        const float* a = W_state + (size_t)(k-128)*H_;
        float s = 0.f;
        for (int t = 0; t < 128; ++t) s += a[t] * Whead[(128+t)*H_ + col];
        v = s;
    } else {
        const float* a = W_top + (size_t)(k-256)*H_;
        float s = 0.f;
        for (int t = 0; t < 128; ++t) s += a[t] * Whead[(256+t)*H_ + col];
        v = s;
    }
    ws[WS_FWM + k*NCOL + j] = v;

    if (j < 3) {
        float v2;
        if (k < 128) v2 = W_mem[k*3 + j];
        else if (k < 256) {
            const float* a = W_state + (size_t)(k-128)*H_;
            float s = 0.f;
            for (int t = 0; t < 128; ++t) s += a[t] * W_mem[(128+t)*3 + j];
            v2 = s;
        } else {
            const float* a = W_top + (size_t)(k-256)*H_;
            float s = 0.f;
            for (int t = 0; t < 128; ++t) s += a[t] * W_mem[(256+t)*3 + j];
            v2 = s;
        }
        ws[WS_FWMEM + k*3 + j] = v2;
    }
    if (k == 0) {
        float s = bhead[col];
        for (int t = 0; t < 128; ++t)
            s += b_state[t]*Whead[(128+t)*H_ + col] + b_top[t]*Whead[(256+t)*H_ + col];
        ws[WS_BIASM + j] = s;
        if (j < 3) {
            float s2 = b_mem[j];
            for (int t = 0; t < 128; ++t)
                s2 += b_state[t]*W_mem[(128+t)*3 + j] + b_top[t]*W_mem[(256+t)*3 + j];
            ws[WS_BIASMEM + j] = s2;
        }
    }
}

template<bool NT>
__device__ __forceinline__ void stencil_body(
    const f32x4* __restrict__ sp, f32x4* __restrict__ op,
    float p0, float p1, float p2, int d0)
{
    auto LD = [&](int d) -> f32x4 {
        const f32x4* p = sp + (size_t)d*32;
        if constexpr (NT) return __builtin_nontemporal_load(p);
        else              return *p;
    };
    f32x4 cur  = LD(d0);
    f32x4 prev = (d0 == 0) ? cur : LD(d0-1);
    #pragma unroll
    for (int h = 0; h < 2; ++h) {
        int base = d0 + h*8;
        f32x4 nx[8];
        #pragma unroll
        for (int i = 0; i < 8; ++i) {
            int d = base + i + 1;
            if (d < 64) nx[i] = LD(d);
            else        nx[i] = (f32x4){0.f, 0.f, 0.f, 0.f};
        }
        #pragma unroll
        for (int i = 0; i < 8; ++i) {
            int d = base + i;
            f32x4 o = p0*prev + p1*nx[i] + p2*cur;
            __builtin_nontemporal_store(o, op + (size_t)d*32);
            prev = cur; cur = nx[i];
        }
    }
}

__global__ __launch_bounds__(256) void main_kernel(
    const float* __restrict__ stack, const float* __restrict__ state_prev,
    const float* __restrict__ x_emb, const float* __restrict__ ws,
    float* __restrict__ out)
{
    int tid = threadIdx.x;
    __shared__ float act[BROWS * ACT_PAD];   // 24.8 KB (GEMM role)
    __shared__ float psh[2][3];              // (stencil role)

    if (blockIdx.x < NB_GEMM) {
        // ---- GEMM role: LDS-staged activations + 4x4 register tile ----
        int b0 = blockIdx.x * BROWS;

        #pragma unroll
        for (int s = 0; s < 3; ++s) {
            #pragma unroll
            for (int it = 0; it < 2; ++it) {
                int idx = it*256 + tid;        // 0..511
                int r   = idx >> 5;            // 0..15
                int kk  = (idx & 31) << 2;     // 0..124
                const float* src;
                if (s == 0)      src = x_emb      + (size_t)(b0+r)*H_;
                else if (s == 1) src = state_prev + (size_t)(b0+r)*H_;
                else             src = stack      + (size_t)(b0+r)*(D_*W_);
                f32x4 v = *(const f32x4*)(src + kk);
                *(f32x4*)(act + r*ACT_PAD + s*128 + kk) = v;
            }
        }
        __syncthreads();

        int rg = tid & 3;          // row group
        int cg = tid >> 2;         // col group
        const float* __restrict__ FW = ws + WS_FWM;
        f32x4 bj = *(const f32x4*)(ws + WS_BIASM + 4*cg);
        float acc[4][4];
        #pragma unroll
        for (int r = 0; r < 4; ++r) {
            acc[r][0] = bj.x; acc[r][1] = bj.y; acc[r][2] = bj.z; acc[r][3] = bj.w;
        }
        const float* a0p = act + (4*rg+0)*ACT_PAD;
        const float* a1p = act + (4*rg+1)*ACT_PAD;
        const float* a2p = act + (4*rg+2)*ACT_PAD;
        const float* a3p = act + (4*rg+3)*ACT_PAD;

        #pragma unroll 4
        for (int k = 0; k < 384; ++k) {
            f32x4 w = *(const f32x4*)(FW + (size_t)k*NCOL + 4*cg);
            float a0 = a0p[k], a1 = a1p[k], a2 = a2p[k], a3 = a3p[k];
            acc[0][0] += a0*w.x; acc[0][1] += a0*w.y; acc[0][2] += a0*w.z; acc[0][3] += a0*w.w;
            acc[1][0] += a1*w.x; acc[1][1] += a1*w.y; acc[1][2] += a1*w.z; acc[1][3] += a1*w.w;
            acc[2][0] += a2*w.x; acc[2][1] += a2*w.y; acc[2][2] += a2*w.z; acc[2][3] += a2*w.w;
            acc[3][0] += a3*w.x; acc[3][1] += a3*w.y; acc[3][2] += a3*w.z; acc[3][3] += a3*w.w;
        }

        #pragma unroll
        for (int r = 0; r < 4; ++r) {
            size_t row = (size_t)(b0 + 4*rg + r);
            if (cg < 32) {
                f32x4 o = {acc[r][0], acc[r][1], acc[r][2], acc[r][3]};
                __builtin_nontemporal_store(o, (f32x4*)(out + OUT_BUF + row*H_ + 4*cg));
            } else {
                f32x4 o = {tanhf(acc[r][0]), tanhf(acc[r][1]),
                           tanhf(acc[r][2]), tanhf(acc[r][3])};
                __builtin_nontemporal_store(o, (f32x4*)(out + OUT_STATE + row*H_ + (4*cg - 128)));
            }
        }
    } else {
        // ---- Stencil role: wave-reduce probs head + barrier-free stream ----
        int blk  = blockIdx.x - NB_GEMM;     // 0..4095
        int wv   = tid >> 6;
        int lane = tid & 63;

        if ((wv & 1) == 0) {                 // waves 0,2 compute probs for rows 0,1
            int bb = blk*2 + (wv >> 1);
            const float* __restrict__ FM = ws + WS_FWMEM;
            float a0 = 0.f, a1 = 0.f, a2 = 0.f;
            int kbase = lane * 6;
            #pragma unroll
            for (int jj = 0; jj < 6; ++jj) {
                int k = kbase + jj;
                float x;
                if (k < 128)      x = x_emb[(size_t)bb*H_ + k];
                else if (k < 256) x = state_prev[(size_t)bb*H_ + (k-128)];
                else              x = stack[(size_t)bb*(D_*W_) + (k-256)];
                a0 += x * FM[k*3+0];
                a1 += x * FM[k*3+1];
                a2 += x * FM[k*3+2];
            }
            #pragma unroll
            for (int m = 1; m < 64; m <<= 1) {
                a0 += __shfl_xor(a0, m);
                a1 += __shfl_xor(a1, m);
                a2 += __shfl_xor(a2, m);
            }
            if (lane == 0) {
                float l0 = a0 + ws[WS_BIASMEM+0];
                float l1 = a1 + ws[WS_BIASMEM+1];
                float l2 = a2 + ws[WS_BIASMEM+2];
                float mm = fmaxf(l0, fmaxf(l1, l2));
                float e0 = __expf(l0-mm), e1 = __expf(l1-mm), e2 = __expf(l2-mm);
                float inv = 1.f / (e0+e1+e2);
                int ro = wv >> 1;
                psh[ro][0] = e0*inv; psh[ro][1] = e1*inv; psh[ro][2] = e2*inv;
                __builtin_nontemporal_store(e0*inv, out + OUT_PROBS + (size_t)bb*3 + 0);
                __builtin_nontemporal_store(e1*inv, out + OUT_PROBS + (size_t)bb*3 + 1);
                __builtin_nontemporal_store(e2*inv, out + OUT_PROBS + (size_t)bb*3 + 2);
            }
        }
        __syncthreads();

        int w4  = tid & 31;                  // float4 index within width-128 row
        int seg = (tid >> 5) & 3;            // depth segment of 16
        int bo  = tid >> 7;                  // 0..1
        size_t b = (size_t)blk * 2 + bo;
        float p0 = psh[bo][0], p1 = psh[bo][1], p2 = psh[bo][2];

        const f32x4* sp = (const f32x4*)(stack + b*(D_*W_)) + w4;
        f32x4*       op = (f32x4*)(out + OUT_STACK + b*(D_*W_)) + w4;
        int d0 = seg * 16;

        if (b < B_CACHED) stencil_body<false>(sp, op, p0, p1, p2, d0);
        else              stencil_body<true >(sp, op, p0, p1, p2, d0);
    }
}

extern "C" void kernel_launch(void* const* d_in, const int* in_sizes, int n_in,
                              void* d_out, int out_size, void* d_ws, size_t ws_size,
                              hipStream_t stream) {
    const float* stack      = (const float*)d_in[0];
    const float* state_prev = (const float*)d_in[1];
    const float* x_emb      = (const float*)d_in[2];
    const float* W_state    = (const float*)d_in[3];
    const float* b_state    = (const float*)d_in[4];
    const float* W_top      = (const float*)d_in[5];
    const float* b_top      = (const float*)d_in[6];
    const float* W_mem      = (const float*)d_in[7];
    const float* b_mem      = (const float*)d_in[8];
    const float* W_buf      = (const float*)d_in[9];
    const float* b_buf      = (const float*)d_in[10];
    const float* W_stateout = (const float*)d_in[11];
    const float* b_stateout = (const float*)d_in[12];
    float* out = (float*)d_out;
    float* ws  = (float*)d_ws;

    hipLaunchKernelGGL(fold_kernel, dim3(384), dim3(256), 0, stream,
        W_state, b_state, W_top, b_top, W_mem, b_mem,
        W_buf, b_buf, W_stateout, b_stateout, ws);
    hipLaunchKernelGGL(main_kernel, dim3(NB_GEMM + NB_STEN), dim3(256), 0, stream,
        stack, state_prev, x_emb, ws, out);
}

// Round 9
// 109.353 us; speedup vs baseline: 1.3422x; 1.0307x over previous
//
#include <hip/hip_runtime.h>
#include <math.h>

#define B_TOT 8192
#define D_ 64
#define W_ 128
#define H_ 128
#define NCOL 256

typedef float f32x4 __attribute__((ext_vector_type(4)));

// ws float offsets
#define WS_FWM     0        // 384*256 folded main weights (k-major)
#define WS_FWMEM   98304    // 384*3 folded mem-head weights
#define WS_BIASM   99456    // 256 folded main bias
#define WS_BIASMEM 99712    // 3 folded mem bias

// out float offsets (return order: stack_new, next_state, logits_buf, action_probs)
#define OUT_STACK 0
#define OUT_STATE 67108864UL
#define OUT_BUF   68157440UL
#define OUT_PROBS 69206016UL

#define NB_GEMM 512
#define NB_STEN 4096   // 2 batch rows per block
#define BROWS 16
#define ACT_PAD 388    // 384 + 4 pad
#define B_CACHED 6656  // rows < this: normal (L3-resident) loads; >=: nontemporal stream

__global__ __launch_bounds__(256) void fold_kernel(
    const float* __restrict__ W_state, const float* __restrict__ b_state,
    const float* __restrict__ W_top,   const float* __restrict__ b_top,
    const float* __restrict__ W_mem,   const float* __restrict__ b_mem,
    const float* __restrict__ W_buf,   const float* __restrict__ b_buf,
    const float* __restrict__ W_stateout, const float* __restrict__ b_stateout,
    float* __restrict__ ws)
{
    int k = blockIdx.x;   // 0..383
    int j = threadIdx.x;  // 0..255
    int col = j & 127;
    const float* Whead = (j < 128) ? W_buf : W_stateout;
    const float* bhead = (j < 128) ? b_buf : b_stateout;
    float v;
    if (k < 128) {
        v = Whead[k*H_ + col];
    } else if (k < 256) {
        const float* a = W_state + (size_t)(k-128)*H_;
        float s = 0.f;
        for (int t = 0; t < 128; ++t) s += a[t] * Whead[(128+t)*H_ + col];
        v = s;
    } else {
        const float* a = W_top + (size_t)(k-256)*H_;
        float s = 0.f;
        for (int t = 0; t < 128; ++t) s += a[t] * Whead[(256+t)*H_ + col];
        v = s;
    }
    ws[WS_FWM + k*NCOL + j] = v;

    if (j < 3) {
        float v2;
        if (k < 128) v2 = W_mem[k*3 + j];
        else if (k < 256) {
            const float* a = W_state + (size_t)(k-128)*H_;
            float s = 0.f;
            for (int t = 0; t < 128; ++t) s += a[t] * W_mem[(128+t)*3 + j];
            v2 = s;
        } else {
            const float* a = W_top + (size_t)(k-256)*H_;
            float s = 0.f;
            for (int t = 0; t < 128; ++t) s += a[t] * W_mem[(256+t)*3 + j];
            v2 = s;
        }
        ws[WS_FWMEM + k*3 + j] = v2;
    }
    if (k == 0) {
        float s = bhead[col];
        for (int t = 0; t < 128; ++t)
            s += b_state[t]*Whead[(128+t)*H_ + col] + b_top[t]*Whead[(256+t)*H_ + col];
        ws[WS_BIASM + j] = s;
        if (j < 3) {
            float s2 = b_mem[j];
            for (int t = 0; t < 128; ++t)
                s2 += b_state[t]*W_mem[(128+t)*3 + j] + b_top[t]*W_mem[(256+t)*3 + j];
            ws[WS_BIASMEM + j] = s2;
        }
    }
}

template<bool NT>
__device__ __forceinline__ void stencil_body(
    const f32x4* __restrict__ sp, f32x4* __restrict__ op,
    float p0, float p1, float p2, int d0)
{
    auto LD = [&](int d) -> f32x4 {
        const f32x4* p = sp + (size_t)d*32;
        if constexpr (NT) return __builtin_nontemporal_load(p);
        else              return *p;
    };
    f32x4 cur  = LD(d0);
    f32x4 prev = (d0 == 0) ? cur : LD(d0-1);
    #pragma unroll
    for (int h = 0; h < 2; ++h) {
        int base = d0 + h*8;
        f32x4 nx[8];
        #pragma unroll
        for (int i = 0; i < 8; ++i) {
            int d = base + i + 1;
            if (d < 64) nx[i] = LD(d);
            else        nx[i] = (f32x4){0.f, 0.f, 0.f, 0.f};
        }
        #pragma unroll
        for (int i = 0; i < 8; ++i) {
            int d = base + i;
            f32x4 o = p0*prev + p1*nx[i] + p2*cur;
            __builtin_nontemporal_store(o, op + (size_t)d*32);
            prev = cur; cur = nx[i];
        }
    }
}

__global__ __launch_bounds__(256) void main_kernel(
    const float* __restrict__ stack, const float* __restrict__ state_prev,
    const float* __restrict__ x_emb, const float* __restrict__ ws,
    float* __restrict__ out)
{
    int tid = threadIdx.x;
    __shared__ float act[BROWS * ACT_PAD];   // 24.8 KB (GEMM role)
    __shared__ float psh[2][3];              // (stencil role)

    if (blockIdx.x < NB_GEMM) {
        // ---- GEMM role: LDS-staged activations + 4x4 register tile ----
        int b0 = blockIdx.x * BROWS;

        #pragma unroll
        for (int s = 0; s < 3; ++s) {
            #pragma unroll
            for (int it = 0; it < 2; ++it) {
                int idx = it*256 + tid;        // 0..511
                int r   = idx >> 5;            // 0..15
                int kk  = (idx & 31) << 2;     // 0..124
                const float* src;
                if (s == 0)      src = x_emb      + (size_t)(b0+r)*H_;
                else if (s == 1) src = state_prev + (size_t)(b0+r)*H_;
                else             src = stack      + (size_t)(b0+r)*(D_*W_);
                f32x4 v = *(const f32x4*)(src + kk);
                *(f32x4*)(act + r*ACT_PAD + s*128 + kk) = v;
            }
        }
        __syncthreads();

        int rg = tid & 3;          // row group
        int cg = tid >> 2;         // col group
        const float* __restrict__ FW = ws + WS_FWM;
        f32x4 bj = *(const f32x4*)(ws + WS_BIASM + 4*cg);
        float acc[4][4];
        #pragma unroll
        for (int r = 0; r < 4; ++r) {
            acc[r][0] = bj.x; acc[r][1] = bj.y; acc[r][2] = bj.z; acc[r][3] = bj.w;
        }
        const float* a0p = act + (4*rg+0)*ACT_PAD;
        const float* a1p = act + (4*rg+1)*ACT_PAD;
        const float* a2p = act + (4*rg+2)*ACT_PAD;
        const float* a3p = act + (4*rg+3)*ACT_PAD;

        #pragma unroll 4
        for (int k = 0; k < 384; ++k) {
            f32x4 w = *(const f32x4*)(FW + (size_t)k*NCOL + 4*cg);
            float a0 = a0p[k], a1 = a1p[k], a2 = a2p[k], a3 = a3p[k];
            acc[0][0] += a0*w.x; acc[0][1] += a0*w.y; acc[0][2] += a0*w.z; acc[0][3] += a0*w.w;
            acc[1][0] += a1*w.x; acc[1][1] += a1*w.y; acc[1][2] += a1*w.z; acc[1][3] += a1*w.w;
            acc[2][0] += a2*w.x; acc[2][1] += a2*w.y; acc[2][2] += a2*w.z; acc[2][3] += a2*w.w;
            acc[3][0] += a3*w.x; acc[3][1] += a3*w.y; acc[3][2] += a3*w.z; acc[3][3] += a3*w.w;
        }

        #pragma unroll
        for (int r = 0; r < 4; ++r) {
            size_t row = (size_t)(b0 + 4*rg + r);
            if (cg < 32) {
                f32x4 o = {acc[r][0], acc[r][1], acc[r][2], acc[r][3]};
                __builtin_nontemporal_store(o, (f32x4*)(out + OUT_BUF + row*H_ + 4*cg));
            } else {
                f32x4 o = {tanhf(acc[r][0]), tanhf(acc[r][1]),
                           tanhf(acc[r][2]), tanhf(acc[r][3])};
                __builtin_nontemporal_store(o, (f32x4*)(out + OUT_STATE + row*H_ + (4*cg - 128)));
            }
        }
    } else {
        // ---- Stencil role: wave-reduce probs head + barrier-free stream ----
        int blk  = blockIdx.x - NB_GEMM;     // 0..4095
        int wv   = tid >> 6;
        int lane = tid & 63;

        if ((wv & 1) == 0) {                 // waves 0,2 compute probs for rows 0,1
            int bb = blk*2 + (wv >> 1);
            const float* __restrict__ FM = ws + WS_FWMEM;
            float a0 = 0.f, a1 = 0.f, a2 = 0.f;
            int kbase = lane * 6;
            #pragma unroll
            for (int jj = 0; jj < 6; ++jj) {
                int k = kbase + jj;
                float x;
                if (k < 128)      x = x_emb[(size_t)bb*H_ + k];
                else if (k < 256) x = state_prev[(size_t)bb*H_ + (k-128)];
                else              x = stack[(size_t)bb*(D_*W_) + (k-256)];
                a0 += x * FM[k*3+0];
                a1 += x * FM[k*3+1];
                a2 += x * FM[k*3+2];
            }
            #pragma unroll
            for (int m = 1; m < 64; m <<= 1) {
                a0 += __shfl_xor(a0, m);
                a1 += __shfl_xor(a1, m);
                a2 += __shfl_xor(a2, m);
            }
            if (lane == 0) {
                float l0 = a0 + ws[WS_BIASMEM+0];
                float l1 = a1 + ws[WS_BIASMEM+1];
                float l2 = a2 + ws[WS_BIASMEM+2];
                float mm = fmaxf(l0, fmaxf(l1, l2));
                float e0 = __expf(l0-mm), e1 = __expf(l1-mm), e2 = __expf(l2-mm);
                float inv = 1.f / (e0+e1+e2);
                int ro = wv >> 1;
                psh[ro][0] = e0*inv; psh[ro][1] = e1*inv; psh[ro][2] = e2*inv;
                __builtin_nontemporal_store(e0*inv, out + OUT_PROBS + (size_t)bb*3 + 0);
                __builtin_nontemporal_store(e1*inv, out + OUT_PROBS + (size_t)bb*3 + 1);
                __builtin_nontemporal_store(e2*inv, out + OUT_PROBS + (size_t)bb*3 + 2);
            }
        }
        __syncthreads();

        int w4  = tid & 31;                  // float4 index within width-128 row
        int seg = (tid >> 5) & 3;            // depth segment of 16
        int bo  = tid >> 7;                  // 0..1
        size_t b = (size_t)blk * 2 + bo;
        float p0 = psh[bo][0], p1 = psh[bo][1], p2 = psh[bo][2];

        const f32x4* sp = (const f32x4*)(stack + b*(D_*W_)) + w4;
        f32x4*       op = (f32x4*)(out + OUT_STACK + b*(D_*W_)) + w4;
        int d0 = seg * 16;

        if (b < B_CACHED) stencil_body<false>(sp, op, p0, p1, p2, d0);
        else              stencil_body<true >(sp, op, p0, p1, p2, d0);
    }
}

extern "C" void kernel_launch(void* const* d_in, const int* in_sizes, int n_in,
                              void* d_out, int out_size, void* d_ws, size_t ws_size,
                              hipStream_t stream) {
    const float* stack      = (const float*)d_in[0];
    const float* state_prev = (const float*)d_in[1];
    const float* x_emb      = (const float*)d_in[2];
    const float* W_state    = (const float*)d_in[3];
    const float* b_state    = (const float*)d_in[4];
    const float* W_top      = (const float*)d_in[5];
    const float* b_top      = (const float*)d_in[6];
    const float* W_mem      = (const float*)d_in[7];
    const float* b_mem      = (const float*)d_in[8];
    const float* W_buf      = (const float*)d_in[9];
    const float* b_buf      = (const float*)d_in[10];
    const float* W_stateout = (const float*)d_in[11];
    const float* b_stateout = (const float*)d_in[12];
    float* out = (float*)d_out;
    float* ws  = (float*)d_ws;

    hipLaunchKernelGGL(fold_kernel, dim3(384), dim3(256), 0, stream,
        W_state, b_state, W_top, b_top, W_mem, b_mem,
        W_buf, b_buf, W_stateout, b_stateout, ws);
    hipLaunchKernelGGL(main_kernel, dim3(NB_GEMM + NB_STEN), dim3(256), 0, stream,
        stack, state_prev, x_emb, ws, out);
}